// Round 14
// baseline (620.392 us; speedup 1.0000x reference)
//
#include <hip/hip_runtime.h>
#include <hip/hip_fp16.h>

#define TT 512
#define HH 128

typedef _Float16 half2_t __attribute__((ext_vector_type(2)));
typedef _Float16 half4_t __attribute__((ext_vector_type(4)));
typedef _Float16 half8_t __attribute__((ext_vector_type(8)));
typedef float    float4_t __attribute__((ext_vector_type(4)));

__device__ __forceinline__ half2_t h2(float v) {
    half2_t r; r[0] = (_Float16)v; r[1] = (_Float16)v; return r;
}
__device__ __forceinline__ half2_t pkrtz(float a, float b) {
    return __builtin_bit_cast(half2_t, __builtin_amdgcn_cvt_pkrtz(a, b));
}

// ---- packed-f16 polynomial activations (no transcendentals) ----
#define TC1 0.994940f
#define TC3 -0.290799f
#define TC5 0.065507f
#define TC7 -0.0062464f
#define SC1 0.2487350f
#define SC3 -0.0181749f
#define SC5 0.00102355f
#define SC7 -0.0000244141f

__device__ __forceinline__ half2_t tanh_pk(half2_t x) {
    half2_t m = __builtin_elementwise_min(__builtin_elementwise_max(x, h2(-2.0f)), h2(2.0f));
    half2_t t = m * m;
    half2_t p = h2(TC7) * t + h2(TC5);
    p = p * t + h2(TC3);
    p = p * t + h2(TC1);
    return m * p;
}
__device__ __forceinline__ half2_t sigma_pk(half2_t x) {
    half2_t m = __builtin_elementwise_min(__builtin_elementwise_max(x, h2(-4.0f)), h2(4.0f));
    half2_t t = m * m;
    half2_t p = h2(SC7) * t + h2(SC5);
    p = p * t + h2(SC3);
    p = p * t + h2(SC1);
    return m * p + h2(0.5f);
}

// LDS-only barrier: waits lgkmcnt(0), leaves global loads/stores in flight.
__device__ __forceinline__ void wg_barrier_lds() {
#if __has_builtin(__builtin_amdgcn_s_waitcnt)
    __builtin_amdgcn_s_waitcnt(0xC07F);   // lgkmcnt(0), vmcnt=max, expcnt=max
#else
    asm volatile("s_waitcnt lgkmcnt(0)" ::: "memory");
#endif
    __builtin_amdgcn_s_barrier();
}

// xp layout (f16), 4-wave rec convention: half index =
//   ((dirbg*512 + t) * 8192) + (w2*64 + lane)*32 + s*16 + T*4 + r
// i.e. each rec lane reads 64 B contiguous per step (4 x half8).
// GEMM wave w_g (0..7) maps to (w2 = w_g>>1, s = w_g&1).

// ---- kernel 1: block-staged xp GEMM (r11 structure, new store offsets).
__global__ __attribute__((amdgpu_flat_work_group_size(512, 512), amdgpu_waves_per_eu(2, 2)))
void xp_gemm_kernel(
    const int* __restrict__ x, const float* __restrict__ emb,
    const float* __restrict__ Wih_f, const float* __restrict__ bih_f, const float* __restrict__ bhh_f,
    const float* __restrict__ Wih_b, const float* __restrict__ bih_b, const float* __restrict__ bhh_b,
    _Float16* __restrict__ xp)
{
    const int wg  = blockIdx.x;        // dirbg
    const int dir = wg >> 3, bg = wg & 7;
    const int tb  = blockIdx.y * 16;   // t-base

    const float* Wih = dir ? Wih_b : Wih_f;
    const float* bih = dir ? bih_b : bih_f;
    const float* bhh = dir ? bhh_b : bhh_f;

    const int tid = threadIdx.x;
    const int w = tid >> 6, lane = tid & 63, lq = lane >> 4, lm = lane & 15;

    __shared__ int id_sm[256];                 // [chain][t]
    __shared__ _Float16 Esm[256 * 136];        // [t*16+chain][col], +8 pad

    if (tid < 256)
        id_sm[tid] = x[(size_t)(bg * 16 + (tid >> 4)) * TT + tb + (tid & 15)];

    half8_t awih[4][4];
    #pragma unroll
    for (int T = 0; T < 4; ++T) {
        #pragma unroll
        for (int kk = 0; kk < 4; ++kk) {
            const float4* s = (const float4*)(Wih + (size_t)(T * 128 + w * 16 + lm) * 128 + kk * 32 + lq * 8);
            float4 v0 = s[0], v1 = s[1];
            half8_t h;
            half2_t a = pkrtz(v0.x, v0.y), b = pkrtz(v0.z, v0.w);
            half2_t c = pkrtz(v1.x, v1.y), d = pkrtz(v1.z, v1.w);
            h[0]=a[0]; h[1]=a[1]; h[2]=b[0]; h[3]=b[1];
            h[4]=c[0]; h[5]=c[1]; h[6]=d[0]; h[7]=d[1];
            awih[T][kk] = h;
        }
    }
    float4_t biasv[4];
    #pragma unroll
    for (int T = 0; T < 4; ++T) {
        int g = T * 128 + w * 16 + lq * 4;
        float4 b1 = *(const float4*)(bih + g);
        float4 b2 = *(const float4*)(bhh + g);
        biasv[T] = (float4_t){b1.x + b2.x, b1.y + b2.y, b1.z + b2.z, b1.w + b2.w};
    }
    __syncthreads();   // id_sm ready

    {   // stage phase: 2 threads per (chain,t) row, 16 float4 each
        const int r  = tid >> 1;
        const int hf = tid & 1;
        const int chain = r >> 4, tt2 = r & 15;
        const float* src = emb + (size_t)id_sm[r] * 128 + hf * 64;
        float4 v[16];
        #pragma unroll
        for (int j = 0; j < 16; ++j) v[j] = *(const float4*)(src + 4 * j);
        _Float16* dst = &Esm[(tt2 * 16 + chain) * 136 + hf * 64];
        #pragma unroll
        for (int j = 0; j < 16; ++j) {
            half2_t a = pkrtz(v[j].x, v[j].y), b = pkrtz(v[j].z, v[j].w);
            half4_t q; q[0]=a[0]; q[1]=a[1]; q[2]=b[0]; q[3]=b[1];
            *(half4_t*)(dst + 4 * j) = q;
        }
    }
    __syncthreads();   // Esm ready; read-only below

    const int w2 = w >> 1, sgl = w & 1;
    #pragma unroll 4
    for (int i = 0; i < 16; ++i) {
        half8_t bfr[4];
        #pragma unroll
        for (int kk = 0; kk < 4; ++kk)
            bfr[kk] = *(const half8_t*)&Esm[(i * 16 + lm) * 136 + kk * 32 + lq * 8];

        float4_t acc[4];
        #pragma unroll
        for (int T = 0; T < 4; ++T) acc[T] = biasv[T];
        #pragma unroll
        for (int kk = 0; kk < 4; ++kk)
            #pragma unroll
            for (int T = 0; T < 4; ++T)
                acc[T] = __builtin_amdgcn_mfma_f32_16x16x32_f16(awih[T][kk], bfr[kk], acc[T], 0, 0, 0);

        half8_t p0, p1;
        {
            half2_t a = pkrtz(acc[0][0], acc[0][1]), b = pkrtz(acc[0][2], acc[0][3]);
            half2_t c = pkrtz(acc[1][0], acc[1][1]), d = pkrtz(acc[1][2], acc[1][3]);
            p0[0]=a[0]; p0[1]=a[1]; p0[2]=b[0]; p0[3]=b[1];
            p0[4]=c[0]; p0[5]=c[1]; p0[6]=d[0]; p0[7]=d[1];
        }
        {
            half2_t a = pkrtz(acc[2][0], acc[2][1]), b = pkrtz(acc[2][2], acc[2][3]);
            half2_t c = pkrtz(acc[3][0], acc[3][1]), d = pkrtz(acc[3][2], acc[3][3]);
            p1[0]=a[0]; p1[1]=a[1]; p1[2]=b[0]; p1[3]=b[1];
            p1[4]=c[0]; p1[5]=c[1]; p1[6]=d[0]; p1[7]=d[1];
        }
        _Float16* dstb = xp + ((size_t)wg * 512 + (tb + i)) * 8192
                            + (size_t)(w2 * 64 + lane) * 32 + sgl * 16;
        half8_t* dst = (half8_t*)dstb;
        dst[0] = p0; dst[1] = p1;
    }
}

// ---- kernel 2: 4-wave recurrence. 16 WGs x 256 thr. Wave w owns hdims
// [32w, 32w+32) via two 16-wide gate subtiles s=0,1. Halving the wave count
// halves the per-step LDS h-read traffic (32->16 KB) and de-duplicates the
// act VALU (1 wave/SIMD, no co-wave issue contention). A-frags: 128 VGPRs
// (waves_per_eu(1,1) -> 512-VGPR budget, no spill per m08).
__global__ __attribute__((amdgpu_flat_work_group_size(256, 256), amdgpu_waves_per_eu(1, 1)))
void bilstm_rec_kernel(
    const _Float16* __restrict__ xp,
    const float* __restrict__ Whh_f, const float* __restrict__ Whh_b,
    float* __restrict__ pooled)
{
    const int wg  = blockIdx.x;        // 0..15 dirbg
    const int dir = wg >> 3, bg = wg & 7;
    const float* Whh = dir ? Whh_b : Whh_f;

    const int tid = threadIdx.x;
    const int w = tid >> 6, lane = tid & 63, lq = lane >> 4, lm = lane & 15;

    __shared__ _Float16 hsm[2][16 * 136];   // [buf][chain][hdim], +8 halfs pad

    // A-frags: gates T*128 + w*32 + s*16 + lm  (2 s x 4 T x 4 kk = 128 VGPRs)
    half8_t awhh[2][4][4];
    #pragma unroll
    for (int s = 0; s < 2; ++s)
        #pragma unroll
        for (int T = 0; T < 4; ++T)
            #pragma unroll
            for (int kk = 0; kk < 4; ++kk) {
                const float4* sp = (const float4*)(Whh + (size_t)(T * 128 + w * 32 + s * 16 + lm) * 128 + kk * 32 + lq * 8);
                float4 v0 = sp[0], v1 = sp[1];
                half8_t h;
                half2_t a = pkrtz(v0.x, v0.y), b = pkrtz(v0.z, v0.w);
                half2_t c = pkrtz(v1.x, v1.y), d = pkrtz(v1.z, v1.w);
                h[0]=a[0]; h[1]=a[1]; h[2]=b[0]; h[3]=b[1];
                h[4]=c[0]; h[5]=c[1]; h[6]=d[0]; h[7]=d[1];
                awhh[s][T][kk] = h;
            }

    for (int k = tid; k < 2 * 16 * 136; k += 256)
        ((_Float16*)hsm)[k] = (_Float16)0.0f;

    // per-lane xp base: 64 B contiguous per step
    const _Float16* xp_wl = xp + (size_t)wg * 512 * 8192 + (size_t)(w * 64 + lane) * 32;

    // rotating 4-deep prefetch buffers (4 half8 each), lead 2
    half8_t Q[4][4];
    {
        int ta = dir ? (TT - 1) : 0;
        const half8_t* p = (const half8_t*)(xp_wl + (size_t)ta * 8192);
        Q[0][0] = p[0]; Q[0][1] = p[1]; Q[0][2] = p[2]; Q[0][3] = p[3];
    }
    {
        int ta = dir ? (TT - 2) : 1;
        const half8_t* p = (const half8_t*)(xp_wl + (size_t)ta * 8192);
        Q[1][0] = p[0]; Q[1][1] = p[1]; Q[1][2] = p[2]; Q[1][3] = p[3];
    }
    __syncthreads();

    half2_t cst[2][2] = {{h2(0.0f), h2(0.0f)}, {h2(0.0f), h2(0.0f)}};
    half2_t hmx[2][2] = {{h2(-60000.0f), h2(-60000.0f)}, {h2(-60000.0f), h2(-60000.0f)}};

    for (int tbs = 0; tbs < TT; tbs += 4) {
        #pragma unroll
        for (int P = 0; P < 4; ++P) {
            const int t = tbs + P;
            {   // prefetch xp(t+2) into slot (P+2)&3
                int tl = (t + 2 < TT) ? (t + 2) : (TT - 1);
                int ta = dir ? (TT - 1 - tl) : tl;
                const half8_t* pp = (const half8_t*)(xp_wl + (size_t)ta * 8192);
                int sl = (P + 2) & 3;
                Q[sl][0] = pp[0]; Q[sl][1] = pp[1]; Q[sl][2] = pp[2]; Q[sl][3] = pp[3];
            }

            // h B-frags (n = chain = lm): 4x ds_read_b128 (16 KB/step WG-wide)
            half8_t bh[4];
            #pragma unroll
            for (int kk = 0; kk < 4; ++kk)
                bh[kk] = *(const half8_t*)&hsm[P & 1][lm * 136 + kk * 32 + lq * 8];

            // acc init from xp: half j = s*16 + T*4 + r  (half8 #h: j=8h..8h+7)
            float4_t acc[2][4];
            #pragma unroll
            for (int s = 0; s < 2; ++s)
                #pragma unroll
                for (int T = 0; T < 4; ++T) {
                    half8_t q = Q[P][s * 2 + (T >> 1)];
                    int o = (T & 1) * 4;
                    acc[s][T] = (float4_t){(float)q[o], (float)q[o+1], (float)q[o+2], (float)q[o+3]};
                }
            #pragma unroll
            for (int kk = 0; kk < 4; ++kk)
                #pragma unroll
                for (int s = 0; s < 2; ++s)
                    #pragma unroll
                    for (int T = 0; T < 4; ++T)
                        acc[s][T] = __builtin_amdgcn_mfma_f32_16x16x32_f16(awhh[s][T][kk], bh[kk], acc[s][T], 0, 0, 0);

            // packed acts per subtile s: lane owns (chain=lm, hdim=w*32+s*16+lq*4+r)
            #pragma unroll
            for (int s = 0; s < 2; ++s) {
                half2_t i01 = sigma_pk(pkrtz(acc[s][0][0], acc[s][0][1]));
                half2_t i23 = sigma_pk(pkrtz(acc[s][0][2], acc[s][0][3]));
                half2_t f01 = sigma_pk(pkrtz(acc[s][1][0], acc[s][1][1]));
                half2_t f23 = sigma_pk(pkrtz(acc[s][1][2], acc[s][1][3]));
                half2_t g01 = tanh_pk(pkrtz(acc[s][2][0], acc[s][2][1]));
                half2_t g23 = tanh_pk(pkrtz(acc[s][2][2], acc[s][2][3]));
                half2_t o01 = sigma_pk(pkrtz(acc[s][3][0], acc[s][3][1]));
                half2_t o23 = sigma_pk(pkrtz(acc[s][3][2], acc[s][3][3]));

                cst[s][0] = f01 * cst[s][0] + i01 * g01;
                cst[s][1] = f23 * cst[s][1] + i23 * g23;
                half2_t h01 = o01 * tanh_pk(cst[s][0]);
                half2_t h23 = o23 * tanh_pk(cst[s][1]);
                hmx[s][0] = __builtin_elementwise_max(hmx[s][0], h01);
                hmx[s][1] = __builtin_elementwise_max(hmx[s][1], h23);

                half4_t hv4;
                hv4[0] = h01[0]; hv4[1] = h01[1]; hv4[2] = h23[0]; hv4[3] = h23[1];
                *(half4_t*)&hsm[1 - (P & 1)][lm * 136 + w * 32 + s * 16 + lq * 4] = hv4;
            }

            wg_barrier_lds();
        }
    }

    #pragma unroll
    for (int s = 0; s < 2; ++s) {
        float4 o;
        o.x = (float)hmx[s][0][0]; o.y = (float)hmx[s][0][1];
        o.z = (float)hmx[s][1][0]; o.w = (float)hmx[s][1][1];
        *(float4*)&pooled[(size_t)(bg * 16 + lm) * 256 + dir * HH + w * 32 + s * 16 + lq * 4] = o;
    }
}

// ---- kernel 3: pooled (128,256) -> relu(W1·+b1) -> sigmoid(W2·+b2) -> (128,1)
__global__ __launch_bounds__(64) void mlp_kernel(
    const float* __restrict__ pooled, const float* __restrict__ W1,
    const float* __restrict__ b1, const float* __restrict__ W2,
    const float* __restrict__ b2, float* __restrict__ out)
{
    const int b = blockIdx.x;
    const int j = threadIdx.x;
    const float4* p = (const float4*)(pooled + (size_t)b * 256);
    const float4* wv = (const float4*)(W1 + (size_t)j * 256);
    float s = 0.0f;
    #pragma unroll
    for (int q = 0; q < 64; ++q) {
        float4 pv = p[q];
        float4 ww = wv[q];
        s += pv.x * ww.x + pv.y * ww.y + pv.z * ww.z + pv.w * ww.w;
    }
    s += b1[j];
    s = fmaxf(s, 0.0f);
    float v = W2[j] * s;
    #pragma unroll
    for (int off = 32; off; off >>= 1) v += __shfl_down(v, off);
    if (j == 0) out[b] = 1.0f / (1.0f + __expf(-(v + b2[0])));
}

extern "C" void kernel_launch(void* const* d_in, const int* in_sizes, int n_in,
                              void* d_out, int out_size, void* d_ws, size_t ws_size,
                              hipStream_t stream) {
    const int*   x     = (const int*)d_in[0];
    const float* emb   = (const float*)d_in[1];
    const float* Wih_f = (const float*)d_in[2];
    const float* Whh_f = (const float*)d_in[3];
    const float* bih_f = (const float*)d_in[4];
    const float* bhh_f = (const float*)d_in[5];
    const float* Wih_b = (const float*)d_in[6];
    const float* Whh_b = (const float*)d_in[7];
    const float* bih_b = (const float*)d_in[8];
    const float* bhh_b = (const float*)d_in[9];
    const float* W1    = (const float*)d_in[10];
    const float* b1    = (const float*)d_in[11];
    const float* W2    = (const float*)d_in[12];
    const float* b2    = (const float*)d_in[13];
    float* out = (float*)d_out;

    char* ws = (char*)d_ws;
    float*    pooled = (float*)ws;                 // 128 KB
    _Float16* xp     = (_Float16*)(ws + 131072);   // 134.2 MB

    hipLaunchKernelGGL(xp_gemm_kernel, dim3(16, 32), dim3(512), 0, stream,
                       x, emb, Wih_f, bih_f, bhh_f, Wih_b, bih_b, bhh_b, xp);
    hipLaunchKernelGGL(bilstm_rec_kernel, dim3(16), dim3(256), 0, stream,
                       xp, Whh_f, Whh_b, pooled);
    hipLaunchKernelGGL(mlp_kernel, dim3(128), dim3(64), 0, stream,
                       pooled, W1, b1, W2, b2, out);
}

// Round 15
// 474.622 us; speedup vs baseline: 1.3071x; 1.3071x over previous
//
#include <hip/hip_runtime.h>
#include <hip/hip_fp16.h>

#define TT 512
#define HH 128

typedef _Float16 half2_t __attribute__((ext_vector_type(2)));
typedef _Float16 half4_t __attribute__((ext_vector_type(4)));
typedef _Float16 half8_t __attribute__((ext_vector_type(8)));
typedef float    float4_t __attribute__((ext_vector_type(4)));

__device__ __forceinline__ half2_t h2(float v) {
    half2_t r; r[0] = (_Float16)v; r[1] = (_Float16)v; return r;
}
__device__ __forceinline__ half2_t pkrtz(float a, float b) {
    return __builtin_bit_cast(half2_t, __builtin_amdgcn_cvt_pkrtz(a, b));
}

// ---- packed-f16 polynomial activations (no transcendentals) ----
#define TC1 0.994940f
#define TC3 -0.290799f
#define TC5 0.065507f
#define TC7 -0.0062464f
#define SC1 0.2487350f
#define SC3 -0.0181749f
#define SC5 0.00102355f
#define SC7 -0.0000244141f

__device__ __forceinline__ half2_t tanh_pk(half2_t x) {
    half2_t m = __builtin_elementwise_min(__builtin_elementwise_max(x, h2(-2.0f)), h2(2.0f));
    half2_t t = m * m;
    half2_t p = h2(TC7) * t + h2(TC5);
    p = p * t + h2(TC3);
    p = p * t + h2(TC1);
    return m * p;
}
__device__ __forceinline__ half2_t sigma_pk(half2_t x) {
    half2_t m = __builtin_elementwise_min(__builtin_elementwise_max(x, h2(-4.0f)), h2(4.0f));
    half2_t t = m * m;
    half2_t p = h2(SC7) * t + h2(SC5);
    p = p * t + h2(SC3);
    p = p * t + h2(SC1);
    return m * p + h2(0.5f);
}

// LDS-only barrier: waits lgkmcnt(0), leaves global loads/stores in flight.
__device__ __forceinline__ void wg_barrier_lds() {
#if __has_builtin(__builtin_amdgcn_s_waitcnt)
    __builtin_amdgcn_s_waitcnt(0xC07F);   // lgkmcnt(0), vmcnt=max, expcnt=max
#else
    asm volatile("s_waitcnt lgkmcnt(0)" ::: "memory");
#endif
    __builtin_amdgcn_s_barrier();
}

// xp layout (f16): half index = (((dirbg*512 + t)*8 + w)*64 + lane)*16,
// 16 halfs per (t,w,lane) in D-order [T*4+r]. Transposed MFMA convention:
// lane (lq,lm) holds gates T*128 + w*16 + lq*4 + r for chain bg*16+lm.
__device__ __forceinline__ size_t xp_off(int dirbg, int t, int w, int lane) {
    return (((size_t)dirbg * 512 + t) * 8 + w) * 1024 + (size_t)lane * 16;
}

// ---- kernel 1: block-staged xp GEMM (r11, proven ~67us).
__global__ __attribute__((amdgpu_flat_work_group_size(512, 512), amdgpu_waves_per_eu(2, 2)))
void xp_gemm_kernel(
    const int* __restrict__ x, const float* __restrict__ emb,
    const float* __restrict__ Wih_f, const float* __restrict__ bih_f, const float* __restrict__ bhh_f,
    const float* __restrict__ Wih_b, const float* __restrict__ bih_b, const float* __restrict__ bhh_b,
    _Float16* __restrict__ xp)
{
    const int wg  = blockIdx.x;        // dirbg
    const int dir = wg >> 3, bg = wg & 7;
    const int tb  = blockIdx.y * 16;   // t-base

    const float* Wih = dir ? Wih_b : Wih_f;
    const float* bih = dir ? bih_b : bih_f;
    const float* bhh = dir ? bhh_b : bhh_f;

    const int tid = threadIdx.x;
    const int w = tid >> 6, lane = tid & 63, lq = lane >> 4, lm = lane & 15;

    __shared__ int id_sm[256];                 // [chain][t]
    __shared__ _Float16 Esm[256 * 136];        // [t*16+chain][col], +8 pad

    if (tid < 256)
        id_sm[tid] = x[(size_t)(bg * 16 + (tid >> 4)) * TT + tb + (tid & 15)];

    half8_t awih[4][4];
    #pragma unroll
    for (int T = 0; T < 4; ++T) {
        #pragma unroll
        for (int kk = 0; kk < 4; ++kk) {
            const float4* s = (const float4*)(Wih + (size_t)(T * 128 + w * 16 + lm) * 128 + kk * 32 + lq * 8);
            float4 v0 = s[0], v1 = s[1];
            half8_t h;
            half2_t a = pkrtz(v0.x, v0.y), b = pkrtz(v0.z, v0.w);
            half2_t c = pkrtz(v1.x, v1.y), d = pkrtz(v1.z, v1.w);
            h[0]=a[0]; h[1]=a[1]; h[2]=b[0]; h[3]=b[1];
            h[4]=c[0]; h[5]=c[1]; h[6]=d[0]; h[7]=d[1];
            awih[T][kk] = h;
        }
    }
    float4_t biasv[4];
    #pragma unroll
    for (int T = 0; T < 4; ++T) {
        int g = T * 128 + w * 16 + lq * 4;
        float4 b1 = *(const float4*)(bih + g);
        float4 b2 = *(const float4*)(bhh + g);
        biasv[T] = (float4_t){b1.x + b2.x, b1.y + b2.y, b1.z + b2.z, b1.w + b2.w};
    }
    __syncthreads();   // id_sm ready

    {   // stage phase: 2 threads per (chain,t) row, 16 float4 each
        const int r  = tid >> 1;
        const int hf = tid & 1;
        const int chain = r >> 4, tt2 = r & 15;
        const float* src = emb + (size_t)id_sm[r] * 128 + hf * 64;
        float4 v[16];
        #pragma unroll
        for (int j = 0; j < 16; ++j) v[j] = *(const float4*)(src + 4 * j);
        _Float16* dst = &Esm[(tt2 * 16 + chain) * 136 + hf * 64];
        #pragma unroll
        for (int j = 0; j < 16; ++j) {
            half2_t a = pkrtz(v[j].x, v[j].y), b = pkrtz(v[j].z, v[j].w);
            half4_t q; q[0]=a[0]; q[1]=a[1]; q[2]=b[0]; q[3]=b[1];
            *(half4_t*)(dst + 4 * j) = q;
        }
    }
    __syncthreads();   // Esm ready; read-only below -> no more barriers

    #pragma unroll 4
    for (int i = 0; i < 16; ++i) {
        half8_t bfr[4];
        #pragma unroll
        for (int kk = 0; kk < 4; ++kk)
            bfr[kk] = *(const half8_t*)&Esm[(i * 16 + lm) * 136 + kk * 32 + lq * 8];

        float4_t acc[4];
        #pragma unroll
        for (int T = 0; T < 4; ++T) acc[T] = biasv[T];
        #pragma unroll
        for (int kk = 0; kk < 4; ++kk)
            #pragma unroll
            for (int T = 0; T < 4; ++T)
                acc[T] = __builtin_amdgcn_mfma_f32_16x16x32_f16(awih[T][kk], bfr[kk], acc[T], 0, 0, 0);

        half8_t p0, p1;
        {
            half2_t a = pkrtz(acc[0][0], acc[0][1]), b = pkrtz(acc[0][2], acc[0][3]);
            half2_t c = pkrtz(acc[1][0], acc[1][1]), d = pkrtz(acc[1][2], acc[1][3]);
            p0[0]=a[0]; p0[1]=a[1]; p0[2]=b[0]; p0[3]=b[1];
            p0[4]=c[0]; p0[5]=c[1]; p0[6]=d[0]; p0[7]=d[1];
        }
        {
            half2_t a = pkrtz(acc[2][0], acc[2][1]), b = pkrtz(acc[2][2], acc[2][3]);
            half2_t c = pkrtz(acc[3][0], acc[3][1]), d = pkrtz(acc[3][2], acc[3][3]);
            p1[0]=a[0]; p1[1]=a[1]; p1[2]=b[0]; p1[3]=b[1];
            p1[4]=c[0]; p1[5]=c[1]; p1[6]=d[0]; p1[7]=d[1];
        }
        half8_t* dst = (half8_t*)(xp + xp_off(wg, tb + i, w, lane));
        dst[0] = p0; dst[1] = p1;
    }
}

// ---- kernel 2: recurrence (r10 8-wave structure — proven best at 334us).
// Change vs r10: MFMA starts from a persistent zero-C quad; xp is added
// post-MFMA in packed f16 (8 pk_add replace 16 v_cvt_f32_f16 per lane/step).
__global__ __attribute__((amdgpu_flat_work_group_size(512, 512), amdgpu_waves_per_eu(2, 2)))
void bilstm_rec_kernel(
    const _Float16* __restrict__ xp,
    const float* __restrict__ Whh_f, const float* __restrict__ Whh_b,
    float* __restrict__ pooled)
{
    const int wg  = blockIdx.x;        // 0..15 dirbg
    const int dir = wg >> 3, bg = wg & 7;
    const float* Whh = dir ? Whh_b : Whh_f;

    const int tid = threadIdx.x;
    const int w = tid >> 6, lane = tid & 63, lq = lane >> 4, lm = lane & 15;

    __shared__ _Float16 hsm[2][16 * 136];   // [buf][chain][hdim], +8 halfs pad

    half8_t awhh[4][4];
    #pragma unroll
    for (int T = 0; T < 4; ++T) {
        #pragma unroll
        for (int kk = 0; kk < 4; ++kk) {
            const float4* s = (const float4*)(Whh + (size_t)(T * 128 + w * 16 + lm) * 128 + kk * 32 + lq * 8);
            float4 v0 = s[0], v1 = s[1];
            half8_t h;
            half2_t a = pkrtz(v0.x, v0.y), b = pkrtz(v0.z, v0.w);
            half2_t c = pkrtz(v1.x, v1.y), d = pkrtz(v1.z, v1.w);
            h[0]=a[0]; h[1]=a[1]; h[2]=b[0]; h[3]=b[1];
            h[4]=c[0]; h[5]=c[1]; h[6]=d[0]; h[7]=d[1];
            awhh[T][kk] = h;
        }
    }

    for (int k = tid; k < 2 * 16 * 136; k += 512)
        ((_Float16*)hsm)[k] = (_Float16)0.0f;

    const _Float16* xp_wl = xp + ((size_t)wg * 512 * 8 + w) * 1024 + (size_t)lane * 16;

    half8_t Qa[4], Qb[4];
    {
        int ta = dir ? (TT - 1) : 0;
        const half8_t* p = (const half8_t*)(xp_wl + (size_t)ta * 8192);
        Qa[0] = p[0]; Qb[0] = p[1];
    }
    {
        int ta = dir ? (TT - 2) : 1;
        const half8_t* p = (const half8_t*)(xp_wl + (size_t)ta * 8192);
        Qa[1] = p[0]; Qb[1] = p[1];
    }
    __syncthreads();

    const float4_t zz = {0.0f, 0.0f, 0.0f, 0.0f};   // persistent zero C-input
    half2_t c01 = h2(0.0f), c23 = h2(0.0f);
    half2_t hm01 = h2(-60000.0f), hm23 = h2(-60000.0f);

    for (int tbs = 0; tbs < TT; tbs += 4) {
        #pragma unroll
        for (int P = 0; P < 4; ++P) {
            const int t = tbs + P;
            {   // prefetch xp(t+2) into buffer (P+2)&3
                int tl = (t + 2 < TT) ? (t + 2) : (TT - 1);
                int ta = dir ? (TT - 1 - tl) : tl;
                const half8_t* pp = (const half8_t*)(xp_wl + (size_t)ta * 8192);
                Qa[(P + 2) & 3] = pp[0]; Qb[(P + 2) & 3] = pp[1];
            }

            half8_t bh[4];
            #pragma unroll
            for (int kk = 0; kk < 4; ++kk)
                bh[kk] = *(const half8_t*)&hsm[P & 1][lm * 136 + kk * 32 + lq * 8];

            // MFMA from zero-C; xp added post-MFMA in f16
            float4_t acc[4];
            #pragma unroll
            for (int T = 0; T < 4; ++T)
                acc[T] = __builtin_amdgcn_mfma_f32_16x16x32_f16(awhh[T][0], bh[0], zz, 0, 0, 0);
            #pragma unroll
            for (int kk = 1; kk < 4; ++kk)
                #pragma unroll
                for (int T = 0; T < 4; ++T)
                    acc[T] = __builtin_amdgcn_mfma_f32_16x16x32_f16(awhh[T][kk], bh[kk], acc[T], 0, 0, 0);

            // xp half2 views (alias Q's VGPRs; no conversion instructions)
            half2_t qa0 = __builtin_shufflevector(Qa[P], Qa[P], 0, 1);
            half2_t qa1 = __builtin_shufflevector(Qa[P], Qa[P], 2, 3);
            half2_t qa2 = __builtin_shufflevector(Qa[P], Qa[P], 4, 5);
            half2_t qa3 = __builtin_shufflevector(Qa[P], Qa[P], 6, 7);
            half2_t qb0 = __builtin_shufflevector(Qb[P], Qb[P], 0, 1);
            half2_t qb1 = __builtin_shufflevector(Qb[P], Qb[P], 2, 3);
            half2_t qb2 = __builtin_shufflevector(Qb[P], Qb[P], 4, 5);
            half2_t qb3 = __builtin_shufflevector(Qb[P], Qb[P], 6, 7);

            half2_t i01 = sigma_pk(pkrtz(acc[0][0], acc[0][1]) + qa0);
            half2_t i23 = sigma_pk(pkrtz(acc[0][2], acc[0][3]) + qa1);
            half2_t f01 = sigma_pk(pkrtz(acc[1][0], acc[1][1]) + qa2);
            half2_t f23 = sigma_pk(pkrtz(acc[1][2], acc[1][3]) + qa3);
            half2_t g01 = tanh_pk(pkrtz(acc[2][0], acc[2][1]) + qb0);
            half2_t g23 = tanh_pk(pkrtz(acc[2][2], acc[2][3]) + qb1);
            half2_t o01 = sigma_pk(pkrtz(acc[3][0], acc[3][1]) + qb2);
            half2_t o23 = sigma_pk(pkrtz(acc[3][2], acc[3][3]) + qb3);

            c01 = f01 * c01 + i01 * g01;
            c23 = f23 * c23 + i23 * g23;
            half2_t h01 = o01 * tanh_pk(c01);
            half2_t h23 = o23 * tanh_pk(c23);
            hm01 = __builtin_elementwise_max(hm01, h01);
            hm23 = __builtin_elementwise_max(hm23, h23);

            half4_t hv4;
            hv4[0] = h01[0]; hv4[1] = h01[1]; hv4[2] = h23[0]; hv4[3] = h23[1];
            *(half4_t*)&hsm[1 - (P & 1)][lm * 136 + w * 16 + lq * 4] = hv4;

            wg_barrier_lds();
        }
    }

    float4 o;
    o.x = (float)hm01[0]; o.y = (float)hm01[1];
    o.z = (float)hm23[0]; o.w = (float)hm23[1];
    *(float4*)&pooled[(size_t)(bg * 16 + lm) * 256 + dir * HH + w * 16 + lq * 4] = o;
}

// ---- kernel 3: pooled (128,256) -> relu(W1·+b1) -> sigmoid(W2·+b2) -> (128,1)
__global__ __launch_bounds__(64) void mlp_kernel(
    const float* __restrict__ pooled, const float* __restrict__ W1,
    const float* __restrict__ b1, const float* __restrict__ W2,
    const float* __restrict__ b2, float* __restrict__ out)
{
    const int b = blockIdx.x;
    const int j = threadIdx.x;
    const float4* p = (const float4*)(pooled + (size_t)b * 256);
    const float4* wv = (const float4*)(W1 + (size_t)j * 256);
    float s = 0.0f;
    #pragma unroll
    for (int q = 0; q < 64; ++q) {
        float4 pv = p[q];
        float4 ww = wv[q];
        s += pv.x * ww.x + pv.y * ww.y + pv.z * ww.z + pv.w * ww.w;
    }
    s += b1[j];
    s = fmaxf(s, 0.0f);
    float v = W2[j] * s;
    #pragma unroll
    for (int off = 32; off; off >>= 1) v += __shfl_down(v, off);
    if (j == 0) out[b] = 1.0f / (1.0f + __expf(-(v + b2[0])));
}

extern "C" void kernel_launch(void* const* d_in, const int* in_sizes, int n_in,
                              void* d_out, int out_size, void* d_ws, size_t ws_size,
                              hipStream_t stream) {
    const int*   x     = (const int*)d_in[0];
    const float* emb   = (const float*)d_in[1];
    const float* Wih_f = (const float*)d_in[2];
    const float* Whh_f = (const float*)d_in[3];
    const float* bih_f = (const float*)d_in[4];
    const float* bhh_f = (const float*)d_in[5];
    const float* Wih_b = (const float*)d_in[6];
    const float* Whh_b = (const float*)d_in[7];
    const float* bih_b = (const float*)d_in[8];
    const float* bhh_b = (const float*)d_in[9];
    const float* W1    = (const float*)d_in[10];
    const float* b1    = (const float*)d_in[11];
    const float* W2    = (const float*)d_in[12];
    const float* b2    = (const float*)d_in[13];
    float* out = (float*)d_out;

    char* ws = (char*)d_ws;
    float*    pooled = (float*)ws;                 // 128 KB
    _Float16* xp     = (_Float16*)(ws + 131072);   // 134.2 MB

    hipLaunchKernelGGL(xp_gemm_kernel, dim3(16, 32), dim3(512), 0, stream,
                       x, emb, Wih_f, bih_f, bhh_f, Wih_b, bih_b, bhh_b, xp);
    hipLaunchKernelGGL(bilstm_rec_kernel, dim3(16), dim3(512), 0, stream,
                       xp, Whh_f, Whh_b, pooled);
    hipLaunchKernelGGL(mlp_kernel, dim3(128), dim3(64), 0, stream,
                       pooled, W1, b1, W2, b2, out);
}